// Round 8
// baseline (934.659 us; speedup 1.0000x reference)
//
#include <hip/hip_runtime.h>
#include <hip/hip_bf16.h>
#include <cstdint>
#include <math.h>

#define N_TOK 8192
#define D_DIM 1024
#define F_DIM 4096
#define NE 8
#define CAP 8192
#define MAXT 72    // max sum_e ceil(cnt_e/256) = 71, padded to 72

typedef __attribute__((ext_vector_type(8))) short short8;
typedef __attribute__((ext_vector_type(4))) short short4v;
typedef __attribute__((ext_vector_type(4))) float f32x4;

__device__ __forceinline__ short f2bf(float f) {
  __bf16 b = (__bf16)f;
  return *(short*)&b;
}
__device__ __forceinline__ float bf2f(short u) {
  union { unsigned int i; float f; } c;
  c.i = ((unsigned int)(unsigned short)u) << 16;
  return c.f;
}

// ---------------- gating + fused X->bf16 ------------------------------------
__global__ __launch_bounds__(256) void gate_kernel(
    const float* __restrict__ X, const float* __restrict__ Wg,
    const float* __restrict__ bg, int* __restrict__ cnt,
    int* __restrict__ bucket, float* __restrict__ pairw,
    unsigned short* __restrict__ Xb)
{
  const int token = blockIdx.x;
  const int tid = threadIdx.x;
  const float4* x4 = (const float4*)(X + (size_t)token * D_DIM);
  const float4* wg4 = (const float4*)Wg;
  float part[NE];
#pragma unroll
  for (int e = 0; e < NE; ++e) part[e] = 0.f;
  const float4 xv = x4[tid];
#pragma unroll
  for (int e = 0; e < NE; ++e) {
    const float4 wv = wg4[e * (D_DIM / 4) + tid];
    part[e] = fmaf(xv.x, wv.x, fmaf(xv.y, wv.y, fmaf(xv.z, wv.z, fmaf(xv.w, wv.w, part[e]))));
  }
  short4v o;
  o.x = f2bf(xv.x); o.y = f2bf(xv.y); o.z = f2bf(xv.z); o.w = f2bf(xv.w);
  ((short4v*)(Xb + (size_t)token * D_DIM))[tid] = o;

#pragma unroll
  for (int e = 0; e < NE; ++e) {
#pragma unroll
    for (int off = 32; off > 0; off >>= 1) part[e] += __shfl_down(part[e], off);
  }
  __shared__ float wsum[4][NE];
  const int wave = tid >> 6;
  if ((tid & 63) == 0) {
#pragma unroll
    for (int e = 0; e < NE; ++e) wsum[wave][e] = part[e];
  }
  __syncthreads();
  if (tid == 0) {
    float lg[NE];
#pragma unroll
    for (int e = 0; e < NE; ++e)
      lg[e] = wsum[0][e] + wsum[1][e] + wsum[2][e] + wsum[3][e] + bg[e];
    int e0 = 0;
#pragma unroll
    for (int e = 1; e < NE; ++e) if (lg[e] > lg[e0]) e0 = e;     // jax tie-break: lower idx
    int e1 = (e0 == 0) ? 1 : 0;
#pragma unroll
    for (int e = 0; e < NE; ++e) if (e != e0 && lg[e] > lg[e1]) e1 = e;
    float p1 = expf(lg[e1] - lg[e0]);            // p0 = 1; softmax denom cancels
    float inv = 1.f / (1.f + p1);
    pairw[token * 2]     = inv;
    pairw[token * 2 + 1] = p1 * inv;
    int pos0 = atomicAdd(&cnt[e0], 1);
    bucket[e0 * CAP + pos0] = token * 2;
    int pos1 = atomicAdd(&cnt[e1], 1);
    bucket[e1 * CAP + pos1] = token * 2 + 1;
  }
}

// ---------------- prefix sums (row offsets + 256-row tile offsets) ----------
__global__ void prefix_kernel(const int* __restrict__ cnt,
                              int* __restrict__ expoff, int* __restrict__ toff)
{
  if (threadIdx.x == 0 && blockIdx.x == 0) {
    int s = 0, t = 0;
#pragma unroll
    for (int e = 0; e < NE; ++e) {
      expoff[e] = s;
      toff[e] = t;
      s += cnt[e];
      t += (cnt[e] + 255) >> 8;
    }
    toff[NE] = t;
  }
}

// ---------------- inverse map: pair -> slot ---------------------------------
__global__ __launch_bounds__(256) void fillslot_kernel(
    const int* __restrict__ cnt, const int* __restrict__ expoff,
    const int* __restrict__ bucket, int* __restrict__ pairslot)
{
  const int e = blockIdx.x;
  const int n = cnt[e], off = expoff[e];
  for (int p = threadIdx.x; p < n; p += 256)
    pairslot[bucket[e * CAP + p]] = off + p;
}

// ---------------- per-expert transpose fp32 [R][C] -> bf16 [C][R] -----------
__global__ __launch_bounds__(256) void transpose_bf16_kernel(
    const float* __restrict__ src, unsigned short* __restrict__ dst, int R, int C)
{
  __shared__ float tileT[64][68];
  const int ez = blockIdx.z;
  src += (size_t)ez * R * C;
  dst += (size_t)ez * R * C;
  const int c0 = blockIdx.x * 64, r0 = blockIdx.y * 64;
  const int tid = threadIdx.x;
  const int cx = tid & 15;
  const int ry = tid >> 4;
#pragma unroll
  for (int i = 0; i < 4; ++i) {
    const int row = ry + i * 16;
    const float4 v = *(const float4*)(src + (size_t)(r0 + row) * C + c0 + cx * 4);
    tileT[cx * 4 + 0][row] = v.x;
    tileT[cx * 4 + 1][row] = v.y;
    tileT[cx * 4 + 2][row] = v.z;
    tileT[cx * 4 + 3][row] = v.w;
  }
  __syncthreads();
#pragma unroll
  for (int i = 0; i < 4; ++i) {
    const int cc = ry + i * 16;
    const float4 v = *(const float4*)(&tileT[cc][cx * 4]);
    short4v o;
    o.x = f2bf(v.x); o.y = f2bf(v.y); o.z = f2bf(v.z); o.w = f2bf(v.w);
    *(short4v*)(dst + (size_t)(c0 + cc) * R + r0 + cx * 4) = o;
  }
}

// ---------------- grouped expert GEMM: 256x256, 8-phase, counted vmcnt ------
// 8 waves (2M x 4N), per-wave 128x64, acc[8][4]. K-half = 256 rows x 32 K
// (16 KB slot); ring of 4 slots per operand (128 KB LDS). Per phase
// (4 phases/K-tile, quadrant = (kk=j>>1, mg=j&1)): ds_read subtile (bf hoisted
// across mg) -> stage ONE K-half (2 DMA insts) -> barrier -> setprio+16 MFMA
// -> [j==3: vmcnt(4)] -> barrier. Ledger: group T stages halves 2T+3 (j=0/1)
// and 2T+4 (j=2/3); slot of half h free after phase 2h+1; vmcnt(4) at j==3
// leaves the 2 newest halves in flight across the group boundary (never 0
// until the tail). Prologue stages h0,h1,h2 then vmcnt(4).
// Read swizzle (lhi^(l15&3))*16 -> 2 lanes/bank (free); DMA source column is
// inverse-swizzled (both-sides rule, proven 0-conflict in R1-R3/R6).
template<int LAYER>
__global__ __launch_bounds__(512) void moe_gemm(
    const unsigned short* __restrict__ Abase,
    const unsigned short* __restrict__ Bt,
    const float* __restrict__ bias,
    const int* __restrict__ cnt,
    const int* __restrict__ expoff,
    const int* __restrict__ toff,
    const int* __restrict__ bucket,
    unsigned short* __restrict__ Obuf)      // hmid (L1) or ybuf (L2)
{
  constexpr int BM = 256, BN = 256, BK = 64;
  constexpr int KDIM = (LAYER == 1) ? D_DIM : F_DIM;
  constexpr int NDIM = (LAYER == 1) ? F_DIM : D_DIM;
  constexpr int KT = KDIM / BK;              // 16 or 64
  constexpr int NH = KDIM / 32;              // total K-halves
  constexpr int NT = NDIM / BN;              // 16 or 4

  const int q = gridDim.x >> 3;
  const int g = (blockIdx.x & 7) * q + (blockIdx.x >> 3);
  const int ntile = g / MAXT;
  const int mt_glob = g % MAXT;
  if (mt_glob >= toff[NE]) return;
  int e = 0;
  while (mt_glob >= toff[e + 1]) ++e;
  const int mtile = mt_glob - toff[e];
  const int cnt_e = cnt[e];
  const int eoff = expoff[e];

  __shared__ __align__(16) char Alds[4 * 16384];   // 64 KiB ring
  __shared__ __align__(16) char Blds[4 * 16384];   // 64 KiB ring
  __shared__ int rowpair[BM];

  const int tid = threadIdx.x;
  const int lane = tid & 63;
  const int l15 = lane & 15, lhi = lane >> 4;
  const int wid = tid >> 6;
  const int uw = __builtin_amdgcn_readfirstlane(wid);
  const int wm = wid >> 2, wn = wid & 3;           // 2M x 4N
  const int swz = (lhi ^ (l15 & 3)) * 16;          // read-side swizzle (bytes)

  if (tid < BM) {
    int pos = mtile * BM + tid;
    rowpair[tid] = (pos < cnt_e) ? bucket[e * CAP + pos] : -1;
  }
  __syncthreads();

  // staging: inst i covers chunks ci = i*512+tid; r = ci>>2 (row), c16 = ci&3;
  // source column sc = c16 ^ (r&3) (inverse swizzle); half h adds h*32 elems.
  const unsigned short* a_base[2];
  const unsigned short* b_base[2];
#pragma unroll
  for (int i = 0; i < 2; ++i) {
    int ci = i * 512 + tid;
    int r = ci >> 2, c16 = ci & 3;
    int sc = c16 ^ (r & 3);
    size_t arow;
    if (LAYER == 1) {
      int pair = rowpair[r];
      arow = (pair < 0) ? 0 : (size_t)(pair >> 1);
    } else {
      arow = (size_t)(eoff + mtile * BM + r);      // contiguous slot rows
    }
    a_base[i] = Abase + arow * KDIM + sc * 8;
    int ng = ntile * BN + r;
    b_base[i] = Bt + (size_t)e * NDIM * KDIM + (size_t)ng * KDIM + sc * 8;
  }

  auto stageA = [&](int h) {
    const int s = h & 3;
#pragma unroll
    for (int i = 0; i < 2; ++i)
      __builtin_amdgcn_global_load_lds(
          (const __attribute__((address_space(1))) uint32_t*)(a_base[i] + h * 32),
          (__attribute__((address_space(3))) uint32_t*)(&Alds[0] + s * 16384 + i * 8192 + uw * 1024),
          16, 0, 0);
  };
  auto stageB = [&](int h) {
    const int s = h & 3;
#pragma unroll
    for (int i = 0; i < 2; ++i)
      __builtin_amdgcn_global_load_lds(
          (const __attribute__((address_space(1))) uint32_t*)(b_base[i] + h * 32),
          (__attribute__((address_space(3))) uint32_t*)(&Blds[0] + s * 16384 + i * 8192 + uw * 1024),
          16, 0, 0);
  };

  f32x4 acc[8][4];
#pragma unroll
  for (int m = 0; m < 8; ++m)
#pragma unroll
    for (int n = 0; n < 4; ++n) acc[m][n] = (f32x4){0.f, 0.f, 0.f, 0.f};

  // prologue: stage halves 0,1,2 (A,B interleaved); keep h2 in flight.
  stageA(0); stageB(0);
  stageA(1); stageB(1);
  stageA(2); stageB(2);
  asm volatile("s_waitcnt vmcnt(4)" ::: "memory");   // h0,h1 landed
  __builtin_amdgcn_sched_barrier(0);
  __builtin_amdgcn_s_barrier();

  short8 bfr[4];
  for (int T = 0; T < KT; ++T) {
#pragma unroll
    for (int j = 0; j < 4; ++j) {
      const int kk = j >> 1, mg = j & 1;
      const int sb = ((2 * T + kk) & 3) * 16384;     // current slot base
      // ds_read: bf hoisted (read only when kk changes), af every phase
      if ((j & 1) == 0) {
#pragma unroll
        for (int n = 0; n < 4; ++n) {
          int row = wn * 64 + n * 16 + l15;
          bfr[n] = *(const short8*)(&Blds[0] + sb + row * 64 + swz);
        }
      }
      short8 af[4];
#pragma unroll
      for (int i = 0; i < 4; ++i) {
        int row = wm * 128 + mg * 64 + i * 16 + l15;
        af[i] = *(const short8*)(&Alds[0] + sb + row * 64 + swz);
      }
      // stage one K-half: j=0,1 -> half 2T+3 (A then B); j=2,3 -> half 2T+4
      {
        const int h = 2 * T + 3 + kk;
        if (h < NH) {
          if ((j & 1) == 0) stageA(h); else stageB(h);
        }
      }
      asm volatile("" ::: "memory");
      __builtin_amdgcn_s_barrier();
      __builtin_amdgcn_s_setprio(1);
#pragma unroll
      for (int i = 0; i < 4; ++i)
#pragma unroll
        for (int n = 0; n < 4; ++n)
          acc[mg * 4 + i][n] =
              __builtin_amdgcn_mfma_f32_16x16x32_bf16(af[i], bfr[n], acc[mg * 4 + i][n], 0, 0, 0);
      __builtin_amdgcn_s_setprio(0);
      if (j == 3) {                                  // once per K-tile
        if (T + 2 < KT) asm volatile("s_waitcnt vmcnt(4)" ::: "memory");
        else            asm volatile("s_waitcnt vmcnt(0)" ::: "memory");
        __builtin_amdgcn_sched_barrier(0);
      }
      asm volatile("" ::: "memory");
      __builtin_amdgcn_s_barrier();
    }
  }

  // epilogue: C/D layout col = lane&15, row = (lane>>4)*4 + j
#pragma unroll
  for (int m = 0; m < 8; ++m) {
#pragma unroll
    for (int j = 0; j < 4; ++j) {
      const int row = wm * 128 + m * 16 + lhi * 4 + j;
      if (mtile * BM + row >= cnt_e) continue;
      const size_t slot = (size_t)(eoff + mtile * BM + row);
#pragma unroll
      for (int n = 0; n < 4; ++n) {
        const int col = ntile * BN + wn * 64 + n * 16 + l15;
        float val = acc[m][n][j] + bias[e * NDIM + col];
        if (LAYER == 1) {
          float gl = 0.5f * val * (1.f + erff(val * 0.70710678118654752f));
          Obuf[slot * F_DIM + col] = (unsigned short)f2bf(gl);
        } else {
          Obuf[slot * D_DIM + col] = (unsigned short)f2bf(val);
        }
      }
    }
  }
}

// ---------------- combine: out[t] = w0*y[slot0] + w1*y[slot1] ---------------
__global__ __launch_bounds__(256) void combine_kernel(
    const unsigned short* __restrict__ ybuf, const float* __restrict__ pairw,
    const int* __restrict__ pairslot, float* __restrict__ out)
{
  const int t = blockIdx.x;
  const int tid = threadIdx.x;
  const float w0 = pairw[t * 2], w1 = pairw[t * 2 + 1];
  const int s0 = pairslot[t * 2], s1 = pairslot[t * 2 + 1];
  const short4v a = ((const short4v*)(ybuf + (size_t)s0 * D_DIM))[tid];
  const short4v b = ((const short4v*)(ybuf + (size_t)s1 * D_DIM))[tid];
  float4 o;
  o.x = w0 * bf2f(a.x) + w1 * bf2f(b.x);
  o.y = w0 * bf2f(a.y) + w1 * bf2f(b.y);
  o.z = w0 * bf2f(a.z) + w1 * bf2f(b.z);
  o.w = w0 * bf2f(a.w) + w1 * bf2f(b.w);
  ((float4*)(out + (size_t)t * D_DIM))[tid] = o;
}

// ---------------- launch ----------------------------------------------------
extern "C" void kernel_launch(void* const* d_in, const int* in_sizes, int n_in,
                              void* d_out, int out_size, void* d_ws, size_t ws_size,
                              hipStream_t stream)
{
  const float* X  = (const float*)d_in[0];
  const float* Wg = (const float*)d_in[1];
  const float* bg = (const float*)d_in[2];
  const float* W1 = (const float*)d_in[3];
  const float* b1 = (const float*)d_in[4];
  const float* W2 = (const float*)d_in[5];
  const float* b2 = (const float*)d_in[6];
  float* out = (float*)d_out;

  char* ws = (char*)d_ws;
  size_t off = 0;
  auto alloc = [&](size_t sz) {
    size_t o = off;
    off = (off + sz + 255) & ~(size_t)255;
    return o;
  };
  int*            cnt      = (int*)(ws + alloc(NE * sizeof(int)));
  int*            expoff   = (int*)(ws + alloc(NE * sizeof(int)));
  int*            toff     = (int*)(ws + alloc((NE + 1) * sizeof(int)));
  int*            bucket   = (int*)(ws + alloc((size_t)NE * CAP * sizeof(int)));
  float*          pairw    = (float*)(ws + alloc((size_t)N_TOK * 2 * sizeof(float)));
  int*            pairslot = (int*)(ws + alloc((size_t)N_TOK * 2 * sizeof(int)));
  unsigned short* Xb       = (unsigned short*)(ws + alloc((size_t)N_TOK * D_DIM * 2));
  unsigned short* W1t      = (unsigned short*)(ws + alloc((size_t)NE * D_DIM * F_DIM * 2));
  unsigned short* W2t      = (unsigned short*)(ws + alloc((size_t)NE * D_DIM * F_DIM * 2));
  unsigned short* hmid     = (unsigned short*)(ws + alloc((size_t)(N_TOK * 2 + 256) * F_DIM * 2));
  unsigned short* ybuf     = W1t;   // W1t dead after GEMM1; ybuf written in GEMM2

  hipMemsetAsync(cnt, 0, NE * sizeof(int), stream);

  transpose_bf16_kernel<<<dim3(F_DIM / 64, D_DIM / 64, NE), 256, 0, stream>>>(
      W1, W1t, D_DIM, F_DIM);
  transpose_bf16_kernel<<<dim3(D_DIM / 64, F_DIM / 64, NE), 256, 0, stream>>>(
      W2, W2t, F_DIM, D_DIM);
  gate_kernel<<<N_TOK, 256, 0, stream>>>(X, Wg, bg, cnt, bucket, pairw, Xb);
  prefix_kernel<<<1, 64, 0, stream>>>(cnt, expoff, toff);
  fillslot_kernel<<<NE, 256, 0, stream>>>(cnt, expoff, bucket, pairslot);

  moe_gemm<1><<<MAXT * (F_DIM / 256), 512, 0, stream>>>(   // 1152 blocks (%8==0)
      Xb, W1t, b1, cnt, expoff, toff, bucket, hmid);
  moe_gemm<2><<<MAXT * (D_DIM / 256), 512, 0, stream>>>(   // 288 blocks (%8==0)
      hmid, W2t, b2, cnt, expoff, toff, bucket, ybuf);
  combine_kernel<<<N_TOK, 256, 0, stream>>>(ybuf, pairw, pairslot, out);
}

// Round 9
// 902.763 us; speedup vs baseline: 1.0353x; 1.0353x over previous
//
#include <hip/hip_runtime.h>
#include <hip/hip_bf16.h>
#include <cstdint>
#include <math.h>

#define N_TOK 8192
#define D_DIM 1024
#define F_DIM 4096
#define NE 8
#define CAP 8192
#define MAXT 136   // max sum_e ceil(cnt_e/128) = 16384/128 + 7 = 135 -> pad 136

typedef __attribute__((ext_vector_type(8))) short short8;
typedef __attribute__((ext_vector_type(4))) short short4v;
typedef __attribute__((ext_vector_type(4))) float f32x4;

__device__ __forceinline__ short f2bf(float f) {
  __bf16 b = (__bf16)f;
  return *(short*)&b;
}
__device__ __forceinline__ float bf2f(short u) {
  union { unsigned int i; float f; } c;
  c.i = ((unsigned int)(unsigned short)u) << 16;
  return c.f;
}
__device__ __forceinline__ void gload(const void* g, void* l) {
  __builtin_amdgcn_global_load_lds(
      (const __attribute__((address_space(1))) uint32_t*)g,
      (__attribute__((address_space(3))) uint32_t*)l, 16, 0, 0);
}

// ---------------- gating + fused X->bf16 ------------------------------------
__global__ __launch_bounds__(256) void gate_kernel(
    const float* __restrict__ X, const float* __restrict__ Wg,
    const float* __restrict__ bg, int* __restrict__ cnt,
    int* __restrict__ bucket, float* __restrict__ pairw,
    unsigned short* __restrict__ Xb)
{
  const int token = blockIdx.x;
  const int tid = threadIdx.x;
  const float4* x4 = (const float4*)(X + (size_t)token * D_DIM);
  const float4* wg4 = (const float4*)Wg;
  float part[NE];
#pragma unroll
  for (int e = 0; e < NE; ++e) part[e] = 0.f;
  const float4 xv = x4[tid];
#pragma unroll
  for (int e = 0; e < NE; ++e) {
    const float4 wv = wg4[e * (D_DIM / 4) + tid];
    part[e] = fmaf(xv.x, wv.x, fmaf(xv.y, wv.y, fmaf(xv.z, wv.z, fmaf(xv.w, wv.w, part[e]))));
  }
  short4v o;
  o.x = f2bf(xv.x); o.y = f2bf(xv.y); o.z = f2bf(xv.z); o.w = f2bf(xv.w);
  ((short4v*)(Xb + (size_t)token * D_DIM))[tid] = o;

#pragma unroll
  for (int e = 0; e < NE; ++e) {
#pragma unroll
    for (int off = 32; off > 0; off >>= 1) part[e] += __shfl_down(part[e], off);
  }
  __shared__ float wsum[4][NE];
  const int wave = tid >> 6;
  if ((tid & 63) == 0) {
#pragma unroll
    for (int e = 0; e < NE; ++e) wsum[wave][e] = part[e];
  }
  __syncthreads();
  if (tid == 0) {
    float lg[NE];
#pragma unroll
    for (int e = 0; e < NE; ++e)
      lg[e] = wsum[0][e] + wsum[1][e] + wsum[2][e] + wsum[3][e] + bg[e];
    int e0 = 0;
#pragma unroll
    for (int e = 1; e < NE; ++e) if (lg[e] > lg[e0]) e0 = e;     // jax tie-break: lower idx
    int e1 = (e0 == 0) ? 1 : 0;
#pragma unroll
    for (int e = 0; e < NE; ++e) if (e != e0 && lg[e] > lg[e1]) e1 = e;
    float p1 = expf(lg[e1] - lg[e0]);            // p0 = 1; softmax denom cancels
    float inv = 1.f / (1.f + p1);
    pairw[token * 2]     = inv;
    pairw[token * 2 + 1] = p1 * inv;
    int pos0 = atomicAdd(&cnt[e0], 1);
    bucket[e0 * CAP + pos0] = token * 2;
    int pos1 = atomicAdd(&cnt[e1], 1);
    bucket[e1 * CAP + pos1] = token * 2 + 1;
  }
}

// ---------------- prefix sums (row offsets + 128-row tile offsets) ----------
__global__ void prefix_kernel(const int* __restrict__ cnt,
                              int* __restrict__ expoff, int* __restrict__ toff)
{
  if (threadIdx.x == 0 && blockIdx.x == 0) {
    int s = 0, t = 0;
#pragma unroll
    for (int e = 0; e < NE; ++e) {
      expoff[e] = s;
      toff[e] = t;
      s += cnt[e];
      t += (cnt[e] + 127) >> 7;
    }
    toff[NE] = t;
  }
}

// ---------------- inverse map: pair -> slot ---------------------------------
__global__ __launch_bounds__(256) void fillslot_kernel(
    const int* __restrict__ cnt, const int* __restrict__ expoff,
    const int* __restrict__ bucket, int* __restrict__ pairslot)
{
  const int e = blockIdx.x;
  const int n = cnt[e], off = expoff[e];
  for (int p = threadIdx.x; p < n; p += 256)
    pairslot[bucket[e * CAP + p]] = off + p;
}

// ---------------- pack weights: fp32 [K][N] -> bf16 swizzled 16KB tiles -----
// Output tile (nt, kt): rows r = n&127, chunks c = (k>>3)&7 stored at
// c ^ (r&7), elems k&7. One tile = 128 rows x 128 B = 16 KB CONTIGUOUS, so
// GEMM staging is a linear stream (DRAM/L2 friendly) and the ds_read XOR
// swizzle (proven 0-conflict R1-R7) needs no source-side work in the GEMM.
__global__ __launch_bounds__(256) void pack_kernel(
    const float* __restrict__ src, unsigned short* __restrict__ dst, int R, int C)
{
  __shared__ float tileT[64][68];
  const int ez = blockIdx.z;
  src += (size_t)ez * R * C;
  char* dbytes = (char*)dst + (size_t)ez * R * C * 2;   // per-expert packed block
  const int c0 = blockIdx.x * 64, r0 = blockIdx.y * 64;
  const int tid = threadIdx.x;
  const int cx = tid & 15;
  const int ry = tid >> 4;
#pragma unroll
  for (int i = 0; i < 4; ++i) {
    const int row = ry + i * 16;
    const float4 v = *(const float4*)(src + (size_t)(r0 + row) * C + c0 + cx * 4);
    tileT[cx * 4 + 0][row] = v.x;
    tileT[cx * 4 + 1][row] = v.y;
    tileT[cx * 4 + 2][row] = v.z;
    tileT[cx * 4 + 3][row] = v.w;
  }
  __syncthreads();
#pragma unroll
  for (int i = 0; i < 4; ++i) {
    const int cc = ry + i * 16;
    const int n = c0 + cc;                 // output row dim (N)
    const int k = r0 + cx * 4;             // output col dim (K), 4 elems
    const float4 v = *(const float4*)(&tileT[cc][cx * 4]);
    short4v o;
    o.x = f2bf(v.x); o.y = f2bf(v.y); o.z = f2bf(v.z); o.w = f2bf(v.w);
    const int nt = n >> 7, r = n & 127;
    const int kt = k >> 6, c = (k >> 3) & 7;
    const size_t byte = ((size_t)nt * (R >> 6) + kt) * 16384 +
                        r * 128 + ((c ^ (r & 7)) << 4) + (k & 7) * 2;
    *(short4v*)(dbytes + byte) = o;
  }
}

// ---------------- grouped expert GEMM: 128x128, dbuf, packed streams --------
// R7 structure exactly (proven: 0 conflicts, VGPR 88, no spills, 2 blocks/CU)
// with packed-contiguous staging:
//   LAYER 1: A = gathered Xb rows (X is 32MB, L3-resident), B = packed W1p;
//            epilogue writes hmidP in GEMM2's packed-A tile format.
//   LAYER 2: A = packed hmidP (linear!), B = packed W2p; writes ybuf.
template<int LAYER>
__global__ __launch_bounds__(256) void moe_gemm(
    const unsigned short* __restrict__ Xb,
    const unsigned short* __restrict__ hmidP,
    const unsigned short* __restrict__ Bpack,
    const float* __restrict__ bias,
    const int* __restrict__ cnt,
    const int* __restrict__ expoff,
    const int* __restrict__ toff,
    const int* __restrict__ bucket,
    unsigned short* __restrict__ OutP,     // hmidP (L1) or ybuf (L2)
    float* __restrict__ unused)
{
  constexpr int BM = 128, BN = 128, BK = 64;
  constexpr int KDIM = (LAYER == 1) ? D_DIM : F_DIM;
  constexpr int NDIM = (LAYER == 1) ? F_DIM : D_DIM;
  constexpr int KT = KDIM / BK;            // 16 or 64
  constexpr int NTP = NDIM / BN;           // 32 or 8

  const int q = gridDim.x >> 3;
  const int g = (blockIdx.x & 7) * q + (blockIdx.x >> 3);
  const int ntile = g / MAXT;
  const int mt_glob = g % MAXT;
  if (mt_glob >= toff[NE]) return;
  int e = 0;
  while (mt_glob >= toff[e + 1]) ++e;
  const int mtile = mt_glob - toff[e];
  const int cnt_e = cnt[e];
  const int eoff = expoff[e];

  __shared__ __align__(16) char Alds[2][16384];   // 32 KiB
  __shared__ __align__(16) char Blds[2][16384];   // 32 KiB
  __shared__ int rowpair[BM];

  const int tid = threadIdx.x;
  const int lane = tid & 63;
  const int l15 = lane & 15, lhi = lane >> 4;
  const int wid = tid >> 6;
  const int uw = __builtin_amdgcn_readfirstlane(wid);
  const int wm = wid >> 1, wn = wid & 1;

  if (LAYER == 1) {
    if (tid < BM) {
      int pos = mtile * BM + tid;
      rowpair[tid] = (pos < cnt_e) ? bucket[e * CAP + pos] : -1;
    }
    __syncthreads();
  }

  // L1 gathered-A sources (source column pre-XOR-swizzled, R7-proven)
  const unsigned short* a_src[4];
  if (LAYER == 1) {
#pragma unroll
    for (int i = 0; i < 4; ++i) {
      int ci = i * 256 + tid;
      int r = ci >> 3, c = ci & 7;
      int sc = c ^ (r & 7);
      int pair = rowpair[r];
      size_t arow = (pair < 0) ? 0 : (size_t)(pair >> 1);
      a_src[i] = Xb + arow * KDIM + sc * 8;
    }
  }
  // packed streams (elements): tile = 8192 shorts, contiguous
  const unsigned short* aP = hmidP + (size_t)mt_glob * 64 * 8192;         // L2 A
  const unsigned short* bP = Bpack +
      ((size_t)e * NTP * KT + (size_t)ntile * KT) * 8192;

  auto stage = [&](int buf, int kt) {
    if (LAYER == 1) {
#pragma unroll
      for (int i = 0; i < 4; ++i)
        gload(a_src[i] + kt * BK, &Alds[buf][0] + i * 4096 + uw * 1024);
    } else {
      const unsigned short* ap = aP + (size_t)kt * 8192;
#pragma unroll
      for (int i = 0; i < 4; ++i)
        gload(ap + (i * 256 + tid) * 8, &Alds[buf][0] + i * 4096 + uw * 1024);
    }
    const unsigned short* bp = bP + (size_t)kt * 8192;
#pragma unroll
    for (int i = 0; i < 4; ++i)
      gload(bp + (i * 256 + tid) * 8, &Blds[buf][0] + i * 4096 + uw * 1024);
  };

  f32x4 acc[4][4];
#pragma unroll
  for (int m = 0; m < 4; ++m)
#pragma unroll
    for (int n = 0; n < 4; ++n) acc[m][n] = (f32x4){0.f, 0.f, 0.f, 0.f};

  stage(0, 0);
  __syncthreads();

  for (int kt = 0; kt < KT; ++kt) {
    const int b = kt & 1;
    if (kt + 1 < KT) stage(b ^ 1, kt + 1);
#pragma unroll
    for (int kk = 0; kk < 2; ++kk) {
      const int c16 = kk * 4 + lhi;
      short8 bfr[4];
#pragma unroll
      for (int n = 0; n < 4; ++n) {
        int row = wn * 64 + n * 16 + l15;
        bfr[n] = *(const short8*)(&Blds[b][0] + row * 128 + ((c16 ^ (row & 7)) * 16));
      }
#pragma unroll
      for (int m = 0; m < 4; ++m) {
        int row = wm * 64 + m * 16 + l15;
        short8 af = *(const short8*)(&Alds[b][0] + row * 128 + ((c16 ^ (row & 7)) * 16));
#pragma unroll
        for (int n = 0; n < 4; ++n)
          acc[m][n] = __builtin_amdgcn_mfma_f32_16x16x32_bf16(af, bfr[n], acc[m][n], 0, 0, 0);
      }
    }
    __syncthreads();
  }

  // epilogue: C/D layout col = lane&15, row = (lane>>4)*4 + j
  char* outBytes = (char*)OutP;
#pragma unroll
  for (int m = 0; m < 4; ++m) {
#pragma unroll
    for (int j = 0; j < 4; ++j) {
      const int row = wm * 64 + m * 16 + lhi * 4 + j;
      if (mtile * BM + row >= cnt_e) continue;
#pragma unroll
      for (int n = 0; n < 4; ++n) {
        const int col = ntile * BN + wn * 64 + n * 16 + l15;
        float val = acc[m][n][j] + bias[e * NDIM + col];
        if (LAYER == 1) {
          float gl = 0.5f * val * (1.f + erff(val * 0.70710678118654752f));
          // write in GEMM2's packed-A format: tile (mt_glob, col>>6)
          const int kt2 = col >> 6, c = (col >> 3) & 7;
          const size_t byte = ((size_t)mt_glob * 64 + kt2) * 16384 +
                              row * 128 + (((c ^ (row & 7))) << 4) + (col & 7) * 2;
          *(unsigned short*)(outBytes + byte) = (unsigned short)f2bf(gl);
        } else {
          const size_t slot = (size_t)(eoff + mtile * BM + row);
          OutP[slot * D_DIM + col] = (unsigned short)f2bf(val);
        }
      }
    }
  }
}

// ---------------- combine: out[t] = w0*y[slot0] + w1*y[slot1] ---------------
__global__ __launch_bounds__(256) void combine_kernel(
    const unsigned short* __restrict__ ybuf, const float* __restrict__ pairw,
    const int* __restrict__ pairslot, float* __restrict__ out)
{
  const int t = blockIdx.x;
  const int tid = threadIdx.x;
  const float w0 = pairw[t * 2], w1 = pairw[t * 2 + 1];
  const int s0 = pairslot[t * 2], s1 = pairslot[t * 2 + 1];
  const short4v a = ((const short4v*)(ybuf + (size_t)s0 * D_DIM))[tid];
  const short4v b = ((const short4v*)(ybuf + (size_t)s1 * D_DIM))[tid];
  float4 o;
  o.x = w0 * bf2f(a.x) + w1 * bf2f(b.x);
  o.y = w0 * bf2f(a.y) + w1 * bf2f(b.y);
  o.z = w0 * bf2f(a.z) + w1 * bf2f(b.z);
  o.w = w0 * bf2f(a.w) + w1 * bf2f(b.w);
  ((float4*)(out + (size_t)t * D_DIM))[tid] = o;
}

// ---------------- launch ----------------------------------------------------
extern "C" void kernel_launch(void* const* d_in, const int* in_sizes, int n_in,
                              void* d_out, int out_size, void* d_ws, size_t ws_size,
                              hipStream_t stream)
{
  const float* X  = (const float*)d_in[0];
  const float* Wg = (const float*)d_in[1];
  const float* bg = (const float*)d_in[2];
  const float* W1 = (const float*)d_in[3];
  const float* b1 = (const float*)d_in[4];
  const float* W2 = (const float*)d_in[5];
  const float* b2 = (const float*)d_in[6];
  float* out = (float*)d_out;

  char* ws = (char*)d_ws;
  size_t off = 0;
  auto alloc = [&](size_t sz) {
    size_t o = off;
    off = (off + sz + 255) & ~(size_t)255;
    return o;
  };
  int*            cnt      = (int*)(ws + alloc(NE * sizeof(int)));
  int*            expoff   = (int*)(ws + alloc(NE * sizeof(int)));
  int*            toff     = (int*)(ws + alloc((NE + 1) * sizeof(int)));
  int*            bucket   = (int*)(ws + alloc((size_t)NE * CAP * sizeof(int)));
  float*          pairw    = (float*)(ws + alloc((size_t)N_TOK * 2 * sizeof(float)));
  int*            pairslot = (int*)(ws + alloc((size_t)N_TOK * 2 * sizeof(int)));
  unsigned short* Xb       = (unsigned short*)(ws + alloc((size_t)N_TOK * D_DIM * 2));
  unsigned short* W1p      = (unsigned short*)(ws + alloc((size_t)NE * D_DIM * F_DIM * 2));
  unsigned short* W2p      = (unsigned short*)(ws + alloc((size_t)NE * D_DIM * F_DIM * 2));
  unsigned short* hmidP    = (unsigned short*)(ws + alloc((size_t)MAXT * 64 * 16384));
  unsigned short* ybuf     = W1p;   // W1p dead after GEMM1

  hipMemsetAsync(cnt, 0, NE * sizeof(int), stream);

  // pack W1 (K=1024 rows, N=4096 cols) and W2 (K=4096 rows, N=1024 cols)
  pack_kernel<<<dim3(F_DIM / 64, D_DIM / 64, NE), 256, 0, stream>>>(
      W1, W1p, D_DIM, F_DIM);
  pack_kernel<<<dim3(D_DIM / 64, F_DIM / 64, NE), 256, 0, stream>>>(
      W2, W2p, F_DIM, D_DIM);
  gate_kernel<<<N_TOK, 256, 0, stream>>>(X, Wg, bg, cnt, bucket, pairw, Xb);
  prefix_kernel<<<1, 64, 0, stream>>>(cnt, expoff, toff);
  fillslot_kernel<<<NE, 256, 0, stream>>>(cnt, expoff, bucket, pairslot);

  moe_gemm<1><<<MAXT * (F_DIM / 128), 256, 0, stream>>>(   // 4352 blocks (%8==0)
      Xb, hmidP, W1p, b1, cnt, expoff, toff, bucket, hmidP, out);
  moe_gemm<2><<<MAXT * (D_DIM / 128), 256, 0, stream>>>(   // 1088 blocks (%8==0)
      Xb, hmidP, W2p, b2, cnt, expoff, toff, bucket, ybuf, out);
  combine_kernel<<<N_TOK, 256, 0, stream>>>(ybuf, pairw, pairslot, out);
}